// Round 2
// baseline (2830.032 us; speedup 1.0000x reference)
//
#include <hip/hip_runtime.h>
#include <hip/hip_bf16.h>

typedef unsigned short u16;
typedef unsigned int u32;
typedef __attribute__((ext_vector_type(8))) __bf16 bf16x8;
typedef __attribute__((ext_vector_type(4))) float f32x4;
typedef __attribute__((ext_vector_type(4))) u16 u16x4;
typedef __attribute__((ext_vector_type(8))) u16 u16x8;

#define SCUR 4096
#define SMEM 16384
#define DM   256
#define DFFN 2048
#define NL   4

__device__ __forceinline__ u16 f2b(float f){
  u32 i; __builtin_memcpy(&i, &f, 4);
  u32 r = (i + 0x7fffu + ((i >> 16) & 1u)) >> 16;
  return (u16)r;
}

__device__ __forceinline__ f32x4 mfma16(bf16x8 a, bf16x8 b, f32x4 c){
  return __builtin_amdgcn_mfma_f32_16x16x32_bf16(a, b, c, 0, 0, 0);
}

// ---------------- elementwise prep ----------------

__global__ void axpy_k(const float* __restrict__ a, const float* __restrict__ b,
                       float s, float* __restrict__ o, int n4){
  int i = blockIdx.x * blockDim.x + threadIdx.x;
  int st = gridDim.x * blockDim.x;
  for (; i < n4; i += st){
    float4 x = ((const float4*)a)[i];
    float4 y = ((const float4*)b)[i];
    float4 r; r.x = x.x + s*y.x; r.y = x.y + s*y.y; r.z = x.z + s*y.z; r.w = x.w + s*y.w;
    ((float4*)o)[i] = r;
  }
}

__global__ void cvt_bf16_k(const float* __restrict__ a, const float* __restrict__ b,
                           u16* __restrict__ o, int n4, float s){
  int i = blockIdx.x * blockDim.x + threadIdx.x;
  int st = gridDim.x * blockDim.x;
  const bool hb = (b != nullptr);
  for (; i < n4; i += st){
    float4 x = ((const float4*)a)[i];
    if (hb){
      float4 y = ((const float4*)b)[i];
      x.x += s*y.x; x.y += s*y.y; x.z += s*y.z; x.w += s*y.w;
    }
    u16x4 r = { f2b(x.x), f2b(x.y), f2b(x.z), f2b(x.w) };
    ((u16x4*)o)[i] = r;
  }
}

// ---------------- layernorm ----------------
template<int OUTF32>
__global__ __launch_bounds__(256) void ln_k(const float* __restrict__ X,
    const float* __restrict__ g, const float* __restrict__ b,
    void* __restrict__ out, int rows){
  int row = blockIdx.x * 4 + (threadIdx.x >> 6);
  int lane = threadIdx.x & 63;
  if (row >= rows) return;
  const float4 v = *(const float4*)(X + (size_t)row*DM + lane*4);
  float s = v.x + v.y + v.z + v.w;
  for (int off = 1; off < 64; off <<= 1) s += __shfl_xor(s, off, 64);
  float mu = s * (1.f/256.f);
  float dx = v.x-mu, dy = v.y-mu, dz = v.z-mu, dw = v.w-mu;
  float q = dx*dx + dy*dy + dz*dz + dw*dw;
  for (int off = 1; off < 64; off <<= 1) q += __shfl_xor(q, off, 64);
  float rstd = rsqrtf(q * (1.f/256.f) + 1e-5f);
  const float4 gw = *(const float4*)(g + lane*4);
  const float4 gb = *(const float4*)(b + lane*4);
  float y0 = dx*rstd*gw.x + gb.x;
  float y1 = dy*rstd*gw.y + gb.y;
  float y2 = dz*rstd*gw.z + gb.z;
  float y3 = dw*rstd*gw.w + gb.w;
  if (OUTF32){
    float4 o; o.x=y0; o.y=y1; o.z=y2; o.w=y3;
    *(float4*)((float*)out + (size_t)row*DM + lane*4) = o;
  } else {
    u16x4 o = { f2b(y0), f2b(y1), f2b(y2), f2b(y3) };
    *(u16x4*)((u16*)out + (size_t)row*DM + lane*4) = o;
  }
}

// ---------------- GEMM: C[M][N] = A[M][K] * W[N][K]^T + bias ----------------
template<int EPI>
__global__ __launch_bounds__(256) void gemm_bt(
    const u16* __restrict__ A, const u16* __restrict__ W,
    const float* __restrict__ bias, void* __restrict__ out,
    int M, int N, int K){
  __shared__ u16 a_sm[64*40];
  __shared__ u16 b_sm[64*40];
  const int tid = threadIdx.x;
  const int lane = tid & 63;
  const int w = tid >> 6;
  const int l16 = lane & 15, lg = lane >> 4;
  const int m0 = blockIdx.y * 64;
  const int n0 = blockIdx.x * 64;
  const int wr = (w >> 1) * 32, wc = (w & 1) * 32;
  f32x4 acc[2][2] = {};
  const int srow = tid >> 2, sch = tid & 3;
  const u16* Ag = A + (size_t)(m0 + srow) * K + sch * 8;
  const u16* Wg = W + (size_t)(n0 + srow) * K + sch * 8;
  for (int k0 = 0; k0 < K; k0 += 32){
    u16x8 av = *(const u16x8*)(Ag + k0);
    u16x8 wv = *(const u16x8*)(Wg + k0);
    __syncthreads();
    *(u16x8*)(a_sm + srow*40 + sch*8) = av;
    *(u16x8*)(b_sm + srow*40 + sch*8) = wv;
    __syncthreads();
    bf16x8 af0 = *(const bf16x8*)(a_sm + (wr      + l16)*40 + lg*8);
    bf16x8 af1 = *(const bf16x8*)(a_sm + (wr + 16 + l16)*40 + lg*8);
    bf16x8 bf0 = *(const bf16x8*)(b_sm + (wc      + l16)*40 + lg*8);
    bf16x8 bf1 = *(const bf16x8*)(b_sm + (wc + 16 + l16)*40 + lg*8);
    acc[0][0] = mfma16(af0, bf0, acc[0][0]);
    acc[0][1] = mfma16(af0, bf1, acc[0][1]);
    acc[1][0] = mfma16(af1, bf0, acc[1][0]);
    acc[1][1] = mfma16(af1, bf1, acc[1][1]);
  }
  for (int mi = 0; mi < 2; mi++)
    for (int ni = 0; ni < 2; ni++)
      for (int r = 0; r < 4; r++){
        int m = m0 + wr + mi*16 + lg*4 + r;
        int n = n0 + wc + ni*16 + l16;
        float v = acc[mi][ni][r] + bias[n];
        if (EPI == 0)      ((u16*)out)[(size_t)m*N + n] = f2b(v);
        else if (EPI == 1) ((u16*)out)[(size_t)m*N + n] = f2b(v > 0.f ? v : 0.f);
        else               ((float*)out)[(size_t)m*N + n] += v;
      }
}

// ---------------- flash attention (single head, hd=256) ----------------
// grid (Sq/64, nsplit), block 256, 2 blocks/CU. Wave w owns 16 q-rows.
// Register-prefetched K/V staging (T14), 4-way-max LDS swizzles.
__global__ __launch_bounds__(256, 2) void flash_k(
    const u16* __restrict__ Q, const u16* __restrict__ K, const u16* __restrict__ V,
    float* __restrict__ Op, float* __restrict__ mp, float* __restrict__ lp,
    int Sq, int kvChunk){
  __shared__ u16 ksm[64*256];   // K tile, rows=key, 16B-chunk XOR swizzled
  __shared__ u16 vtsm[256*64];  // V^T tile, rows=d, swizzled: scv = cv ^ ((d+(d>>3))&7)
  __shared__ u16 psm[4*1024];   // per-wave P tile 16x64, swizzled
  const int tid = threadIdx.x, lane = tid & 63, w = tid >> 6;
  const int l16 = lane & 15, lg = lane >> 4;
  const int qrow0 = blockIdx.x * 64 + w * 16;

  bf16x8 qf[8];
  {
    const u16* qp = Q + (size_t)(qrow0 + l16) * DM + lg * 8;
    #pragma unroll
    for (int ks = 0; ks < 8; ks++) qf[ks] = *(const bf16x8*)(qp + ks*32);
  }
  f32x4 oa[16] = {};
  float mst[4] = {-1e30f, -1e30f, -1e30f, -1e30f};
  float lst[4] = {0.f, 0.f, 0.f, 0.f};
  const int kv0 = blockIdx.y * kvChunk;
  const int nt = kvChunk >> 6;

  // staging assignment
  const int kc  = tid & 31;   // K chunk
  const int kr0 = tid >> 5;   // K base row (+8 per step)
  const u16* Kg = K + (size_t)kv0 * DM;
  const u16* Vg = V + (size_t)kv0 * DM;

  u16x8 krg[8], vrg[8];
  // prologue: load tile 0 into regs
  #pragma unroll
  for (int i = 0; i < 8; i++)
    krg[i] = *(const u16x8*)(Kg + (kr0 + 8*i)*DM + kc*8);
  #pragma unroll
  for (int j = 0; j < 4; j++){
    int task = tid + j*256; int rp = task >> 5; int c = task & 31; int kk = rp*2;
    vrg[2*j]   = *(const u16x8*)(Vg + (size_t)kk*DM + c*8);
    vrg[2*j+1] = *(const u16x8*)(Vg + (size_t)(kk+1)*DM + c*8);
  }

  for (int t = 0; t < nt; t++){
    __syncthreads();   // all waves done reading LDS of previous tile
    // ---- write K tile from regs ----
    #pragma unroll
    for (int i = 0; i < 8; i++){
      int r = kr0 + 8*i;
      int sc = (kc & ~7) | ((kc ^ r) & 7);
      *(u16x8*)(ksm + r*256 + sc*8) = krg[i];
    }
    // ---- write V^T tile from regs (4-way max conflict) ----
    #pragma unroll
    for (int j = 0; j < 4; j++){
      int task = tid + j*256; int rp = task >> 5; int c = task & 31; int kk = rp*2;
      #pragma unroll
      for (int e = 0; e < 8; e++){
        int d = c*8 + e;
        int s = (e + c) & 7;          // == (d + (d>>3)) & 7
        int scv = (kk >> 3) ^ s;
        u32 word = (u32)(u16)vrg[2*j][e] | ((u32)(u16)vrg[2*j+1][e] << 16);
        *(u32*)((char*)vtsm + d*128 + scv*16 + (kk & 7)*2) = word;
      }
    }
    // ---- prefetch tile t+1 into regs (latency hides under compute) ----
    if (t + 1 < nt){
      const u16* Kg2 = Kg + (size_t)(t+1)*64*DM;
      const u16* Vg2 = Vg + (size_t)(t+1)*64*DM;
      #pragma unroll
      for (int i = 0; i < 8; i++)
        krg[i] = *(const u16x8*)(Kg2 + (kr0 + 8*i)*DM + kc*8);
      #pragma unroll
      for (int j = 0; j < 4; j++){
        int task = tid + j*256; int rp = task >> 5; int c = task & 31; int kk = rp*2;
        vrg[2*j]   = *(const u16x8*)(Vg2 + (size_t)kk*DM + c*8);
        vrg[2*j+1] = *(const u16x8*)(Vg2 + (size_t)(kk+1)*DM + c*8);
      }
    }
    __syncthreads();   // LDS tile t ready

    // ---- S = (Q K^T) / 16 ----
    f32x4 sa[4] = {};
    #pragma unroll
    for (int c = 0; c < 4; c++){
      int rk = c*16 + l16;
      #pragma unroll
      for (int ks = 0; ks < 8; ks++){
        int ch = ks*4 + lg;
        int sc = (ch & ~7) | ((ch ^ rk) & 7);
        bf16x8 kf = *(const bf16x8*)(ksm + rk*256 + sc*8);
        sa[c] = mfma16(qf[ks], kf, sa[c]);
      }
    }
    #pragma unroll
    for (int c = 0; c < 4; c++)
      #pragma unroll
      for (int r = 0; r < 4; r++) sa[c][r] *= 0.0625f;

    // ---- online softmax ----
    float alpha[4];
    float pr[4][4];
    #pragma unroll
    for (int r = 0; r < 4; r++){
      float mt = fmaxf(fmaxf(sa[0][r], sa[1][r]), fmaxf(sa[2][r], sa[3][r]));
      for (int off = 1; off < 16; off <<= 1) mt = fmaxf(mt, __shfl_xor(mt, off, 64));
      float mn = fmaxf(mst[r], mt);
      float al = __expf(mst[r] - mn);
      float rs = 0.f;
      #pragma unroll
      for (int c = 0; c < 4; c++){ float pv = __expf(sa[c][r] - mn); pr[c][r] = pv; rs += pv; }
      for (int off = 1; off < 16; off <<= 1) rs += __shfl_xor(rs, off, 64);
      lst[r] = lst[r]*al + rs;
      mst[r] = mn;
      alpha[r] = al;
    }
    #pragma unroll
    for (int dc = 0; dc < 16; dc++)
      #pragma unroll
      for (int r = 0; r < 4; r++) oa[dc][r] *= alpha[r];

    // ---- write P (bf16) to per-wave LDS (no barrier needed: same wave reads) ----
    {
      u16* pw = psm + w*1024;
      #pragma unroll
      for (int c = 0; c < 4; c++)
        #pragma unroll
        for (int r = 0; r < 4; r++){
          int row = lg*4 + r;
          int col = c*16 + l16;
          int ch = col >> 3;
          int sc2 = ch ^ (row & 7);
          pw[row*64 + sc2*8 + (col & 7)] = f2b(pr[c][r]);
        }
    }

    // ---- O += P V ----
    bf16x8 pf[2];
    {
      const u16* pb = psm + w*1024;
      #pragma unroll
      for (int ks2 = 0; ks2 < 2; ks2++){
        int ch = ks2*4 + lg;
        int sc2 = ch ^ (l16 & 7);
        pf[ks2] = *(const bf16x8*)(pb + l16*64 + sc2*8);
      }
    }
    #pragma unroll
    for (int dc = 0; dc < 16; dc++){
      int d = dc*16 + l16;
      int s = (d + (d >> 3)) & 7;
      #pragma unroll
      for (int ks2 = 0; ks2 < 2; ks2++){
        int ch = ks2*4 + lg;
        int sc2 = ch ^ s;
        bf16x8 vf = *(const bf16x8*)(vtsm + d*64 + sc2*8);
        oa[dc] = mfma16(pf[ks2], vf, oa[dc]);
      }
    }
  }

  // partials out
  const int split = blockIdx.y;
  float* Obase = Op + (size_t)split * Sq * DM;
  #pragma unroll
  for (int dc = 0; dc < 16; dc++)
    #pragma unroll
    for (int r = 0; r < 4; r++){
      int q = qrow0 + lg*4 + r;
      int d = dc*16 + l16;
      Obase[(size_t)q*DM + d] = oa[dc][r];
    }
  if (l16 == 0){
    #pragma unroll
    for (int r = 0; r < 4; r++){
      int q = qrow0 + lg*4 + r;
      mp[(size_t)split*Sq + q] = mst[r];
      lp[(size_t)split*Sq + q] = lst[r];
    }
  }
}

// combine KV-split partials -> bf16 O
__global__ __launch_bounds__(256) void combine_k(const float* __restrict__ Op,
    const float* __restrict__ mp, const float* __restrict__ lp,
    u16* __restrict__ Ob, int Sq, int nsplit){
  int q = blockIdx.x;
  int d = threadIdx.x;
  float mM = -1e30f;
  for (int i = 0; i < nsplit; i++) mM = fmaxf(mM, mp[(size_t)i*Sq + q]);
  float Ls = 0.f, acc = 0.f;
  for (int i = 0; i < nsplit; i++){
    float wgt = __expf(mp[(size_t)i*Sq + q] - mM);
    Ls  += lp[(size_t)i*Sq + q] * wgt;
    acc += wgt * Op[((size_t)i*Sq + q)*DM + d];
  }
  Ob[(size_t)q*DM + d] = f2b(acc / Ls);
}

// ---------------- launch ----------------
extern "C" void kernel_launch(void* const* d_in, const int* in_sizes, int n_in,
                              void* d_out, int out_size, void* d_ws, size_t ws_size,
                              hipStream_t stream){
  (void)in_sizes; (void)n_in; (void)out_size;
  const float* curr       = (const float*)d_in[0];
  const float* memory     = (const float*)d_in[1];
  const float* curr_pos   = (const float*)d_in[2];
  const float* memory_pos = (const float*)d_in[3];
  const float* sa_w_qkv   = (const float*)d_in[4];
  const float* sa_b_qkv   = (const float*)d_in[5];
  const float* sa_w_o     = (const float*)d_in[6];
  const float* sa_b_o     = (const float*)d_in[7];
  const float* ca_w_qkv   = (const float*)d_in[8];
  const float* ca_b_qkv   = (const float*)d_in[9];
  const float* ca_w_o     = (const float*)d_in[10];
  const float* ca_b_o     = (const float*)d_in[11];
  const float* ln1_w = (const float*)d_in[12];
  const float* ln1_b = (const float*)d_in[13];
  const float* ln2_w = (const float*)d_in[14];
  const float* ln2_b = (const float*)d_in[15];
  const float* ln3_w = (const float*)d_in[16];
  const float* ln3_b = (const float*)d_in[17];
  const float* mlp_w1 = (const float*)d_in[18];
  const float* mlp_b1 = (const float*)d_in[19];
  const float* mlp_w2 = (const float*)d_in[20];
  const float* mlp_b2 = (const float*)d_in[21];
  const float* norm_w = (const float*)d_in[22];
  const float* norm_b = (const float*)d_in[23];

  // ws gate: NSPLIT=8 needs ~86MB; fall back to 4 (round-1 footprint) otherwise
  const int nsplit = (ws_size >= (size_t)92*1024*1024) ? 8 : 4;

  char* wsp = (char*)d_ws;
  auto alloc = [&](size_t bytes)->void*{
    void* r = (void*)wsp; wsp += (bytes + 255) & ~(size_t)255; return r;
  };
  float* x     = (float*)alloc((size_t)SCUR*DM*4);
  u16*   t2b   = (u16*)  alloc((size_t)SCUR*DM*2);
  u16*   Qb    = (u16*)  alloc((size_t)SCUR*DM*2);
  u16*   Kb    = (u16*)  alloc((size_t)SMEM*DM*2);
  u16*   Vb    = (u16*)  alloc((size_t)SMEM*DM*2);
  u16*   Ob    = (u16*)  alloc((size_t)SCUR*DM*2);
  u16*   memkb = (u16*)  alloc((size_t)SMEM*DM*2);
  u16*   memb  = (u16*)  alloc((size_t)SMEM*DM*2);
  // union: MLP hidden (16MB) aliases attention partials (nsplit*4MB)
  size_t uni_bytes = (size_t)SCUR*DFFN*2;
  size_t op_bytes  = (size_t)nsplit*SCUR*DM*4;
  char*  uni   = (char*) alloc(uni_bytes > op_bytes ? uni_bytes : op_bytes);
  u16*   Hb    = (u16*)uni;
  float* Opart = (float*)uni;
  float* mpart = (float*)alloc((size_t)8*SCUR*4);
  float* lpart = (float*)alloc((size_t)8*SCUR*4);
  u16* wb_sa_qkv = (u16*)alloc((size_t)NL*3*DM*DM*2);
  u16* wb_sa_o   = (u16*)alloc((size_t)NL*DM*DM*2);
  u16* wb_ca_qkv = (u16*)alloc((size_t)NL*3*DM*DM*2);
  u16* wb_ca_o   = (u16*)alloc((size_t)NL*DM*DM*2);
  u16* wb_m1     = (u16*)alloc((size_t)NL*DFFN*DM*2);
  u16* wb_m2     = (u16*)alloc((size_t)NL*DM*DFFN*2);

  const float* nullf = nullptr;

  axpy_k<<<dim3(512), dim3(256), 0, stream>>>(curr, curr_pos, 0.1f, x, SCUR*DM/4);
  cvt_bf16_k<<<dim3(1024), dim3(256), 0, stream>>>(memory, memory_pos, memkb, SMEM*DM/4, 1.0f);
  cvt_bf16_k<<<dim3(1024), dim3(256), 0, stream>>>(memory, nullf, memb, SMEM*DM/4, 0.f);
  cvt_bf16_k<<<dim3(512), dim3(256), 0, stream>>>(sa_w_qkv, nullf, wb_sa_qkv, NL*3*DM*DM/4, 0.f);
  cvt_bf16_k<<<dim3(256), dim3(256), 0, stream>>>(sa_w_o,   nullf, wb_sa_o,   NL*DM*DM/4,   0.f);
  cvt_bf16_k<<<dim3(512), dim3(256), 0, stream>>>(ca_w_qkv, nullf, wb_ca_qkv, NL*3*DM*DM/4, 0.f);
  cvt_bf16_k<<<dim3(256), dim3(256), 0, stream>>>(ca_w_o,   nullf, wb_ca_o,   NL*DM*DM/4,   0.f);
  cvt_bf16_k<<<dim3(1024), dim3(256), 0, stream>>>(mlp_w1,  nullf, wb_m1,     NL*DFFN*DM/4, 0.f);
  cvt_bf16_k<<<dim3(1024), dim3(256), 0, stream>>>(mlp_w2,  nullf, wb_m2,     NL*DM*DFFN/4, 0.f);

  const dim3 blk(256);
  for (int l = 0; l < NL; l++){
    // ---- self attention ----
    ln_k<0><<<dim3(SCUR/4), blk, 0, stream>>>(x, ln1_w + l*DM, ln1_b + l*DM, (void*)t2b, SCUR);
    gemm_bt<0><<<dim3(DM/64, SCUR/64), blk, 0, stream>>>(t2b, wb_sa_qkv + ((size_t)l*3+0)*DM*DM, sa_b_qkv + l*3*DM + 0*DM, (void*)Qb, SCUR, DM, DM);
    gemm_bt<0><<<dim3(DM/64, SCUR/64), blk, 0, stream>>>(t2b, wb_sa_qkv + ((size_t)l*3+1)*DM*DM, sa_b_qkv + l*3*DM + 1*DM, (void*)Kb, SCUR, DM, DM);
    gemm_bt<0><<<dim3(DM/64, SCUR/64), blk, 0, stream>>>(t2b, wb_sa_qkv + ((size_t)l*3+2)*DM*DM, sa_b_qkv + l*3*DM + 2*DM, (void*)Vb, SCUR, DM, DM);
    flash_k<<<dim3(SCUR/64, nsplit), blk, 0, stream>>>(Qb, Kb, Vb, Opart, mpart, lpart, SCUR, SCUR/nsplit);
    combine_k<<<dim3(SCUR), blk, 0, stream>>>(Opart, mpart, lpart, Ob, SCUR, nsplit);
    gemm_bt<2><<<dim3(DM/64, SCUR/64), blk, 0, stream>>>(Ob, wb_sa_o + (size_t)l*DM*DM, sa_b_o + l*DM, (void*)x, SCUR, DM, DM);

    // ---- cross attention ----
    ln_k<0><<<dim3(SCUR/4), blk, 0, stream>>>(x, ln2_w + l*DM, ln2_b + l*DM, (void*)t2b, SCUR);
    gemm_bt<0><<<dim3(DM/64, SCUR/64), blk, 0, stream>>>(t2b,   wb_ca_qkv + ((size_t)l*3+0)*DM*DM, ca_b_qkv + l*3*DM + 0*DM, (void*)Qb, SCUR, DM, DM);
    gemm_bt<0><<<dim3(DM/64, SMEM/64), blk, 0, stream>>>(memkb, wb_ca_qkv + ((size_t)l*3+1)*DM*DM, ca_b_qkv + l*3*DM + 1*DM, (void*)Kb, SMEM, DM, DM);
    gemm_bt<0><<<dim3(DM/64, SMEM/64), blk, 0, stream>>>(memb,  wb_ca_qkv + ((size_t)l*3+2)*DM*DM, ca_b_qkv + l*3*DM + 2*DM, (void*)Vb, SMEM, DM, DM);
    flash_k<<<dim3(SCUR/64, nsplit), blk, 0, stream>>>(Qb, Kb, Vb, Opart, mpart, lpart, SCUR, SMEM/nsplit);
    combine_k<<<dim3(SCUR), blk, 0, stream>>>(Opart, mpart, lpart, Ob, SCUR, nsplit);
    gemm_bt<2><<<dim3(DM/64, SCUR/64), blk, 0, stream>>>(Ob, wb_ca_o + (size_t)l*DM*DM, ca_b_o + l*DM, (void*)x, SCUR, DM, DM);

    // ---- MLP ----
    ln_k<0><<<dim3(SCUR/4), blk, 0, stream>>>(x, ln3_w + l*DM, ln3_b + l*DM, (void*)t2b, SCUR);
    gemm_bt<1><<<dim3(DFFN/64, SCUR/64), blk, 0, stream>>>(t2b, wb_m1 + (size_t)l*DFFN*DM, mlp_b1 + l*DFFN, (void*)Hb, SCUR, DFFN, DM);
    gemm_bt<2><<<dim3(DM/64, SCUR/64), blk, 0, stream>>>(Hb, wb_m2 + (size_t)l*DM*DFFN, mlp_b2 + l*DM, (void*)x, SCUR, DM, DFFN);
  }

  ln_k<1><<<dim3(SCUR/4), blk, 0, stream>>>(x, norm_w, norm_b, d_out, SCUR);
}

// Round 3
// 2482.624 us; speedup vs baseline: 1.1399x; 1.1399x over previous
//
#include <hip/hip_runtime.h>
#include <hip/hip_bf16.h>

typedef unsigned short u16;
typedef unsigned int u32;
typedef __attribute__((ext_vector_type(8))) __bf16 bf16x8;
typedef __attribute__((ext_vector_type(4))) float f32x4;
typedef __attribute__((ext_vector_type(4))) u16 u16x4;
typedef __attribute__((ext_vector_type(8))) u16 u16x8;

#define SCUR 4096
#define SMEM 16384
#define DM   256
#define DFFN 2048
#define NL   4

__device__ __forceinline__ u16 f2b(float f){
  u32 i; __builtin_memcpy(&i, &f, 4);
  u32 r = (i + 0x7fffu + ((i >> 16) & 1u)) >> 16;
  return (u16)r;
}

__device__ __forceinline__ f32x4 mfma16(bf16x8 a, bf16x8 b, f32x4 c){
  return __builtin_amdgcn_mfma_f32_16x16x32_bf16(a, b, c, 0, 0, 0);
}

__device__ __forceinline__ void glds16(const u16* g, u16* l){
  __builtin_amdgcn_global_load_lds(
      (const __attribute__((address_space(1))) u32*)g,
      (__attribute__((address_space(3))) u32*)l, 16, 0, 0);
}

// ---------------- elementwise prep ----------------

__global__ void axpy_k(const float* __restrict__ a, const float* __restrict__ b,
                       float s, float* __restrict__ o, int n4){
  int i = blockIdx.x * blockDim.x + threadIdx.x;
  int st = gridDim.x * blockDim.x;
  for (; i < n4; i += st){
    float4 x = ((const float4*)a)[i];
    float4 y = ((const float4*)b)[i];
    float4 r; r.x = x.x + s*y.x; r.y = x.y + s*y.y; r.z = x.z + s*y.z; r.w = x.w + s*y.w;
    ((float4*)o)[i] = r;
  }
}

__global__ void cvt_bf16_k(const float* __restrict__ a, const float* __restrict__ b,
                           u16* __restrict__ o, int n4, float s){
  int i = blockIdx.x * blockDim.x + threadIdx.x;
  int st = gridDim.x * blockDim.x;
  const bool hb = (b != nullptr);
  for (; i < n4; i += st){
    float4 x = ((const float4*)a)[i];
    if (hb){
      float4 y = ((const float4*)b)[i];
      x.x += s*y.x; x.y += s*y.y; x.z += s*y.z; x.w += s*y.w;
    }
    u16x4 r = { f2b(x.x), f2b(x.y), f2b(x.z), f2b(x.w) };
    ((u16x4*)o)[i] = r;
  }
}

// ---------------- layernorm ----------------
template<int OUTF32>
__global__ __launch_bounds__(256) void ln_k(const float* __restrict__ X,
    const float* __restrict__ g, const float* __restrict__ b,
    void* __restrict__ out, int rows){
  int row = blockIdx.x * 4 + (threadIdx.x >> 6);
  int lane = threadIdx.x & 63;
  if (row >= rows) return;
  const float4 v = *(const float4*)(X + (size_t)row*DM + lane*4);
  float s = v.x + v.y + v.z + v.w;
  for (int off = 1; off < 64; off <<= 1) s += __shfl_xor(s, off, 64);
  float mu = s * (1.f/256.f);
  float dx = v.x-mu, dy = v.y-mu, dz = v.z-mu, dw = v.w-mu;
  float q = dx*dx + dy*dy + dz*dz + dw*dw;
  for (int off = 1; off < 64; off <<= 1) q += __shfl_xor(q, off, 64);
  float rstd = rsqrtf(q * (1.f/256.f) + 1e-5f);
  const float4 gw = *(const float4*)(g + lane*4);
  const float4 gb = *(const float4*)(b + lane*4);
  float y0 = dx*rstd*gw.x + gb.x;
  float y1 = dy*rstd*gw.y + gb.y;
  float y2 = dz*rstd*gw.z + gb.z;
  float y3 = dw*rstd*gw.w + gb.w;
  if (OUTF32){
    float4 o; o.x=y0; o.y=y1; o.z=y2; o.w=y3;
    *(float4*)((float*)out + (size_t)row*DM + lane*4) = o;
  } else {
    u16x4 o = { f2b(y0), f2b(y1), f2b(y2), f2b(y3) };
    *(u16x4*)((u16*)out + (size_t)row*DM + lane*4) = o;
  }
}

// ---------------- GEMM: C[M][N] = A[M][K] * W[N][K]^T + bias ----------------
template<int EPI>
__global__ __launch_bounds__(256) void gemm_bt(
    const u16* __restrict__ A, const u16* __restrict__ W,
    const float* __restrict__ bias, void* __restrict__ out,
    int M, int N, int K){
  __shared__ u16 a_sm[64*40];
  __shared__ u16 b_sm[64*40];
  const int tid = threadIdx.x;
  const int lane = tid & 63;
  const int w = tid >> 6;
  const int l16 = lane & 15, lg = lane >> 4;
  const int m0 = blockIdx.y * 64;
  const int n0 = blockIdx.x * 64;
  const int wr = (w >> 1) * 32, wc = (w & 1) * 32;
  f32x4 acc[2][2] = {};
  const int srow = tid >> 2, sch = tid & 3;
  const u16* Ag = A + (size_t)(m0 + srow) * K + sch * 8;
  const u16* Wg = W + (size_t)(n0 + srow) * K + sch * 8;
  for (int k0 = 0; k0 < K; k0 += 32){
    u16x8 av = *(const u16x8*)(Ag + k0);
    u16x8 wv = *(const u16x8*)(Wg + k0);
    __syncthreads();
    *(u16x8*)(a_sm + srow*40 + sch*8) = av;
    *(u16x8*)(b_sm + srow*40 + sch*8) = wv;
    __syncthreads();
    bf16x8 af0 = *(const bf16x8*)(a_sm + (wr      + l16)*40 + lg*8);
    bf16x8 af1 = *(const bf16x8*)(a_sm + (wr + 16 + l16)*40 + lg*8);
    bf16x8 bf0 = *(const bf16x8*)(b_sm + (wc      + l16)*40 + lg*8);
    bf16x8 bf1 = *(const bf16x8*)(b_sm + (wc + 16 + l16)*40 + lg*8);
    acc[0][0] = mfma16(af0, bf0, acc[0][0]);
    acc[0][1] = mfma16(af0, bf1, acc[0][1]);
    acc[1][0] = mfma16(af1, bf0, acc[1][0]);
    acc[1][1] = mfma16(af1, bf1, acc[1][1]);
  }
  for (int mi = 0; mi < 2; mi++)
    for (int ni = 0; ni < 2; ni++)
      for (int r = 0; r < 4; r++){
        int m = m0 + wr + mi*16 + lg*4 + r;
        int n = n0 + wc + ni*16 + l16;
        float v = acc[mi][ni][r] + bias[n];
        if (EPI == 0)      ((u16*)out)[(size_t)m*N + n] = f2b(v);
        else if (EPI == 1) ((u16*)out)[(size_t)m*N + n] = f2b(v > 0.f ? v : 0.f);
        else               ((float*)out)[(size_t)m*N + n] += v;
      }
}

// ---------------- flash attention (single head, hd=256) ----------------
// 1D grid (64*nsplit): split = bid & (nsplit-1) -> pins split to XCD,
// qtile = bid >> shift. 2 blocks/CU. K staged via global_load_lds with
// pre-swizzled source; V reg-prefetched (t+1) with counted-vmcnt barrier.
__global__ __launch_bounds__(256, 2) void flash_k(
    const u16* __restrict__ Q, int qs,
    const u16* __restrict__ K, int kss,
    const u16* __restrict__ V, int vss,
    float* __restrict__ Op, float* __restrict__ mp, float* __restrict__ lp,
    int Sq, int kvChunk, int shift){
  __shared__ u16 ksm[64*256];   // K tile, XOR-swizzled via pre-swizzled glds source
  __shared__ u16 vtsm[256*64];  // V^T tile, swizzled: scv = cv ^ ((d+(d>>3))&7)
  __shared__ u16 psm[4*1024];   // per-wave P tile 16x64
  const int bid = blockIdx.x;
  const int split = bid & ((1 << shift) - 1);
  const int qtile = bid >> shift;
  const int tid = threadIdx.x, lane = tid & 63, w = tid >> 6;
  const int l16 = lane & 15, lg = lane >> 4;
  const int qrow0 = qtile * 64 + w * 16;

  bf16x8 qf[8];
  {
    const u16* qp = Q + (size_t)(qrow0 + l16) * qs + lg * 8;
    #pragma unroll
    for (int ks = 0; ks < 8; ks++) qf[ks] = *(const bf16x8*)(qp + ks*32);
  }
  f32x4 oa[16] = {};
  float mst[4] = {-1e30f, -1e30f, -1e30f, -1e30f};
  float lst[4] = {0.f, 0.f, 0.f, 0.f};
  const int kv0 = split * kvChunk;
  const int nt = kvChunk >> 6;

  const u16* Kg = K + (size_t)kv0 * kss;
  const u16* Vg = V + (size_t)kv0 * vss;

  // V staging task for this thread (covers 2 key-rows x 8 d each, x4 steps)
  u16x8 vrg[8];
  #pragma unroll
  for (int j = 0; j < 4; j++){
    int task = tid + j*256; int rp = task >> 5; int c = task & 31; int kk = rp*2;
    vrg[2*j]   = *(const u16x8*)(Vg + (size_t)kk*vss + c*8);
    vrg[2*j+1] = *(const u16x8*)(Vg + (size_t)(kk+1)*vss + c*8);
  }

  for (int t = 0; t < nt; t++){
    __syncthreads();   // A: all waves done reading LDS of tile t-1 (drains vmcnt too)

    // ---- K tile via global_load_lds, source pre-swizzled ----
    {
      const u16* Kt = Kg + (size_t)t * 64 * kss;
      #pragma unroll
      for (int i = 0; i < 8; i++){
        int r = w*16 + i*2 + (lane >> 5);
        int sc = lane & 31;
        int c = (sc & ~7) | ((sc ^ r) & 7);
        glds16(Kt + (size_t)r * kss + c*8, ksm + w*4096 + i*512);
      }
      __builtin_amdgcn_sched_barrier(0);   // keep glds oldest in vmcnt FIFO
    }

    // ---- write V^T tile from regs (4-way max conflict) ----
    #pragma unroll
    for (int j = 0; j < 4; j++){
      int task = tid + j*256; int rp = task >> 5; int c = task & 31; int kk = rp*2;
      #pragma unroll
      for (int e = 0; e < 8; e++){
        int d = c*8 + e;
        int s = (e + c) & 7;          // == (d + (d>>3)) & 7
        int scv = (kk >> 3) ^ s;
        u32 word = (u32)(u16)vrg[2*j][e] | ((u32)(u16)vrg[2*j+1][e] << 16);
        *(u32*)((char*)vtsm + d*128 + scv*16 + (kk & 7)*2) = word;
      }
    }

    // ---- prefetch V(t+1) into regs (stays in flight across compute) ----
    if (t + 1 < nt){
      const u16* Vg2 = Vg + (size_t)(t+1) * 64 * vss;
      #pragma unroll
      for (int j = 0; j < 4; j++){
        int task = tid + j*256; int rp = task >> 5; int c = task & 31; int kk = rp*2;
        vrg[2*j]   = *(const u16x8*)(Vg2 + (size_t)kk*vss + c*8);
        vrg[2*j+1] = *(const u16x8*)(Vg2 + (size_t)(kk+1)*vss + c*8);
      }
      asm volatile("s_waitcnt vmcnt(16) lgkmcnt(0)" ::: "memory");  // K done, V(t+1) flying
    } else {
      asm volatile("s_waitcnt vmcnt(0) lgkmcnt(0)" ::: "memory");
    }
    __builtin_amdgcn_s_barrier();   // B: tile t ready in LDS

    // ---- S = (Q K^T) / 16 ----
    f32x4 sa[4] = {};
    #pragma unroll
    for (int c = 0; c < 4; c++){
      int rk = c*16 + l16;
      #pragma unroll
      for (int ks = 0; ks < 8; ks++){
        int ch = ks*4 + lg;
        int sc = (ch & ~7) | ((ch ^ rk) & 7);
        bf16x8 kf = *(const bf16x8*)(ksm + rk*256 + sc*8);
        sa[c] = mfma16(qf[ks], kf, sa[c]);
      }
    }
    #pragma unroll
    for (int c = 0; c < 4; c++)
      #pragma unroll
      for (int r = 0; r < 4; r++) sa[c][r] *= 0.0625f;

    // ---- online softmax ----
    float alpha[4];
    float pr[4][4];
    #pragma unroll
    for (int r = 0; r < 4; r++){
      float mt = fmaxf(fmaxf(sa[0][r], sa[1][r]), fmaxf(sa[2][r], sa[3][r]));
      for (int off = 1; off < 16; off <<= 1) mt = fmaxf(mt, __shfl_xor(mt, off, 64));
      float mn = fmaxf(mst[r], mt);
      float al = __expf(mst[r] - mn);
      float rs = 0.f;
      #pragma unroll
      for (int c = 0; c < 4; c++){ float pv = __expf(sa[c][r] - mn); pr[c][r] = pv; rs += pv; }
      for (int off = 1; off < 16; off <<= 1) rs += __shfl_xor(rs, off, 64);
      lst[r] = lst[r]*al + rs;
      mst[r] = mn;
      alpha[r] = al;
    }
    #pragma unroll
    for (int dc = 0; dc < 16; dc++)
      #pragma unroll
      for (int r = 0; r < 4; r++) oa[dc][r] *= alpha[r];

    // ---- write P (bf16) to per-wave LDS ----
    {
      u16* pw = psm + w*1024;
      #pragma unroll
      for (int c = 0; c < 4; c++)
        #pragma unroll
        for (int r = 0; r < 4; r++){
          int row = lg*4 + r;
          int col = c*16 + l16;
          int ch = col >> 3;
          int sc2 = ch ^ (row & 7);
          pw[row*64 + sc2*8 + (col & 7)] = f2b(pr[c][r]);
        }
    }

    // ---- O += P V ----
    bf16x8 pf[2];
    {
      const u16* pb = psm + w*1024;
      #pragma unroll
      for (int ks2 = 0; ks2 < 2; ks2++){
        int ch = ks2*4 + lg;
        int sc2 = ch ^ (l16 & 7);
        pf[ks2] = *(const bf16x8*)(pb + l16*64 + sc2*8);
      }
    }
    #pragma unroll
    for (int dc = 0; dc < 16; dc++){
      int d = dc*16 + l16;
      int s = (d + (d >> 3)) & 7;
      #pragma unroll
      for (int ks2 = 0; ks2 < 2; ks2++){
        int ch = ks2*4 + lg;
        int sc2 = ch ^ s;
        bf16x8 vf = *(const bf16x8*)(vtsm + d*64 + sc2*8);
        oa[dc] = mfma16(pf[ks2], vf, oa[dc]);
      }
    }
  }

  // partials out
  float* Obase = Op + (size_t)split * Sq * DM;
  #pragma unroll
  for (int dc = 0; dc < 16; dc++)
    #pragma unroll
    for (int r = 0; r < 4; r++){
      int q = qrow0 + lg*4 + r;
      int d = dc*16 + l16;
      Obase[(size_t)q*DM + d] = oa[dc][r];
    }
  if (l16 == 0){
    #pragma unroll
    for (int r = 0; r < 4; r++){
      int q = qrow0 + lg*4 + r;
      mp[(size_t)split*Sq + q] = mst[r];
      lp[(size_t)split*Sq + q] = lst[r];
    }
  }
}

// combine KV-split partials -> bf16 O
__global__ __launch_bounds__(256) void combine_k(const float* __restrict__ Op,
    const float* __restrict__ mp, const float* __restrict__ lp,
    u16* __restrict__ Ob, int Sq, int nsplit){
  int q = blockIdx.x;
  int d = threadIdx.x;
  float mM = -1e30f;
  for (int i = 0; i < nsplit; i++) mM = fmaxf(mM, mp[(size_t)i*Sq + q]);
  float Ls = 0.f, acc = 0.f;
  for (int i = 0; i < nsplit; i++){
    float wgt = __expf(mp[(size_t)i*Sq + q] - mM);
    Ls  += lp[(size_t)i*Sq + q] * wgt;
    acc += wgt * Op[((size_t)i*Sq + q)*DM + d];
  }
  Ob[(size_t)q*DM + d] = f2b(acc / Ls);
}

// ---------------- launch ----------------
extern "C" void kernel_launch(void* const* d_in, const int* in_sizes, int n_in,
                              void* d_out, int out_size, void* d_ws, size_t ws_size,
                              hipStream_t stream){
  (void)in_sizes; (void)n_in; (void)out_size;
  const float* curr       = (const float*)d_in[0];
  const float* memory     = (const float*)d_in[1];
  const float* curr_pos   = (const float*)d_in[2];
  const float* memory_pos = (const float*)d_in[3];
  const float* sa_w_qkv   = (const float*)d_in[4];
  const float* sa_b_qkv   = (const float*)d_in[5];
  const float* sa_w_o     = (const float*)d_in[6];
  const float* sa_b_o     = (const float*)d_in[7];
  const float* ca_w_qkv   = (const float*)d_in[8];
  const float* ca_b_qkv   = (const float*)d_in[9];
  const float* ca_w_o     = (const float*)d_in[10];
  const float* ca_b_o     = (const float*)d_in[11];
  const float* ln1_w = (const float*)d_in[12];
  const float* ln1_b = (const float*)d_in[13];
  const float* ln2_w = (const float*)d_in[14];
  const float* ln2_b = (const float*)d_in[15];
  const float* ln3_w = (const float*)d_in[16];
  const float* ln3_b = (const float*)d_in[17];
  const float* mlp_w1 = (const float*)d_in[18];
  const float* mlp_b1 = (const float*)d_in[19];
  const float* mlp_w2 = (const float*)d_in[20];
  const float* mlp_b2 = (const float*)d_in[21];
  const float* norm_w = (const float*)d_in[22];
  const float* norm_b = (const float*)d_in[23];

  const int nsplit = (ws_size >= (size_t)100*1024*1024) ? 8 : 4;
  const int shift  = (nsplit == 8) ? 3 : 2;

  char* wsp = (char*)d_ws;
  auto alloc = [&](size_t bytes)->void*{
    void* r = (void*)wsp; wsp += (bytes + 255) & ~(size_t)255; return r;
  };
  float* x     = (float*)alloc((size_t)SCUR*DM*4);
  u16*   t2b   = (u16*)  alloc((size_t)SCUR*DM*2);
  u16*   qkvb  = (u16*)  alloc((size_t)SCUR*3*DM*2);   // fused self QKV [S][768]
  u16*   Qb    = (u16*)  alloc((size_t)SCUR*DM*2);
  u16*   Kb    = (u16*)  alloc((size_t)SMEM*DM*2);
  u16*   Vb    = (u16*)  alloc((size_t)SMEM*DM*2);
  u16*   Ob    = (u16*)  alloc((size_t)SCUR*DM*2);
  u16*   memkb = (u16*)  alloc((size_t)SMEM*DM*2);
  u16*   memb  = (u16*)  alloc((size_t)SMEM*DM*2);
  size_t uni_bytes = (size_t)SCUR*DFFN*2;
  size_t op_bytes  = (size_t)nsplit*SCUR*DM*4;
  char*  uni   = (char*) alloc(uni_bytes > op_bytes ? uni_bytes : op_bytes);
  u16*   Hb    = (u16*)uni;
  float* Opart = (float*)uni;
  float* mpart = (float*)alloc((size_t)8*SCUR*4);
  float* lpart = (float*)alloc((size_t)8*SCUR*4);
  u16* wb_sa_qkv = (u16*)alloc((size_t)NL*3*DM*DM*2);
  u16* wb_sa_o   = (u16*)alloc((size_t)NL*DM*DM*2);
  u16* wb_ca_qkv = (u16*)alloc((size_t)NL*3*DM*DM*2);
  u16* wb_ca_o   = (u16*)alloc((size_t)NL*DM*DM*2);
  u16* wb_m1     = (u16*)alloc((size_t)NL*DFFN*DM*2);
  u16* wb_m2     = (u16*)alloc((size_t)NL*DM*DFFN*2);

  const float* nullf = nullptr;

  axpy_k<<<dim3(512), dim3(256), 0, stream>>>(curr, curr_pos, 0.1f, x, SCUR*DM/4);
  cvt_bf16_k<<<dim3(1024), dim3(256), 0, stream>>>(memory, memory_pos, memkb, SMEM*DM/4, 1.0f);
  cvt_bf16_k<<<dim3(1024), dim3(256), 0, stream>>>(memory, nullf, memb, SMEM*DM/4, 0.f);
  cvt_bf16_k<<<dim3(512), dim3(256), 0, stream>>>(sa_w_qkv, nullf, wb_sa_qkv, NL*3*DM*DM/4, 0.f);
  cvt_bf16_k<<<dim3(256), dim3(256), 0, stream>>>(sa_w_o,   nullf, wb_sa_o,   NL*DM*DM/4,   0.f);
  cvt_bf16_k<<<dim3(512), dim3(256), 0, stream>>>(ca_w_qkv, nullf, wb_ca_qkv, NL*3*DM*DM/4, 0.f);
  cvt_bf16_k<<<dim3(256), dim3(256), 0, stream>>>(ca_w_o,   nullf, wb_ca_o,   NL*DM*DM/4,   0.f);
  cvt_bf16_k<<<dim3(1024), dim3(256), 0, stream>>>(mlp_w1,  nullf, wb_m1,     NL*DFFN*DM/4, 0.f);
  cvt_bf16_k<<<dim3(1024), dim3(256), 0, stream>>>(mlp_w2,  nullf, wb_m2,     NL*DM*DFFN/4, 0.f);

  const dim3 blk(256);
  for (int l = 0; l < NL; l++){
    // ---- self attention (fused QKV GEMM: N=768) ----
    ln_k<0><<<dim3(SCUR/4), blk, 0, stream>>>(x, ln1_w + l*DM, ln1_b + l*DM, (void*)t2b, SCUR);
    gemm_bt<0><<<dim3(3*DM/64, SCUR/64), blk, 0, stream>>>(t2b, wb_sa_qkv + (size_t)l*3*DM*DM, sa_b_qkv + (size_t)l*3*DM, (void*)qkvb, SCUR, 3*DM, DM);
    flash_k<<<dim3(64*nsplit), blk, 0, stream>>>(qkvb, 3*DM, qkvb + DM, 3*DM, qkvb + 2*DM, 3*DM,
                                                 Opart, mpart, lpart, SCUR, SCUR/nsplit, shift);
    combine_k<<<dim3(SCUR), blk, 0, stream>>>(Opart, mpart, lpart, Ob, SCUR, nsplit);
    gemm_bt<2><<<dim3(DM/64, SCUR/64), blk, 0, stream>>>(Ob, wb_sa_o + (size_t)l*DM*DM, sa_b_o + l*DM, (void*)x, SCUR, DM, DM);

    // ---- cross attention ----
    ln_k<0><<<dim3(SCUR/4), blk, 0, stream>>>(x, ln2_w + l*DM, ln2_b + l*DM, (void*)t2b, SCUR);
    gemm_bt<0><<<dim3(DM/64, SCUR/64), blk, 0, stream>>>(t2b,   wb_ca_qkv + ((size_t)l*3+0)*DM*DM, ca_b_qkv + l*3*DM + 0*DM, (void*)Qb, SCUR, DM, DM);
    gemm_bt<0><<<dim3(DM/64, SMEM/64), blk, 0, stream>>>(memkb, wb_ca_qkv + ((size_t)l*3+1)*DM*DM, ca_b_qkv + l*3*DM + 1*DM, (void*)Kb, SMEM, DM, DM);
    gemm_bt<0><<<dim3(DM/64, SMEM/64), blk, 0, stream>>>(memb,  wb_ca_qkv + ((size_t)l*3+2)*DM*DM, ca_b_qkv + l*3*DM + 2*DM, (void*)Vb, SMEM, DM, DM);
    flash_k<<<dim3(64*nsplit), blk, 0, stream>>>(Qb, DM, Kb, DM, Vb, DM,
                                                 Opart, mpart, lpart, SCUR, SMEM/nsplit, shift);
    combine_k<<<dim3(SCUR), blk, 0, stream>>>(Opart, mpart, lpart, Ob, SCUR, nsplit);
    gemm_bt<2><<<dim3(DM/64, SCUR/64), blk, 0, stream>>>(Ob, wb_ca_o + (size_t)l*DM*DM, ca_b_o + l*DM, (void*)x, SCUR, DM, DM);

    // ---- MLP ----
    ln_k<0><<<dim3(SCUR/4), blk, 0, stream>>>(x, ln3_w + l*DM, ln3_b + l*DM, (void*)t2b, SCUR);
    gemm_bt<1><<<dim3(DFFN/64, SCUR/64), blk, 0, stream>>>(t2b, wb_m1 + (size_t)l*DFFN*DM, mlp_b1 + l*DFFN, (void*)Hb, SCUR, DFFN, DM);
    gemm_bt<2><<<dim3(DM/64, SCUR/64), blk, 0, stream>>>(Hb, wb_m2 + (size_t)l*DM*DFFN, mlp_b2 + l*DM, (void*)x, SCUR, DM, DFFN);
  }

  ln_k<1><<<dim3(SCUR/4), blk, 0, stream>>>(x, norm_w, norm_b, d_out, SCUR);
}